// Round 8
// baseline (2274.762 us; speedup 1.0000x reference)
//
#include <hip/hip_runtime.h>

#define NTOK  32768
#define NE    8192
#define DIM   256
#define NGRP  8        // 1024 codes per group
#define EPSF  5.0e-4f   // candidate band slack (>= 2*delta bound 3.2e-4 + key quantum)
#define DSELQ 4.8e-4f   // ambiguity bound on quantized keys (4.5e-4 + quantum slop)

typedef __attribute__((ext_vector_type(8))) short short8;
typedef __attribute__((ext_vector_type(4))) float f32x4;

static __device__ __forceinline__ unsigned pk32(float f) {
  unsigned u = __float_as_uint(f);
  return (u & 0x80000000u) ? ~u : (u | 0x80000000u);
}
static __device__ __forceinline__ float upk32(unsigned p) {
  unsigned u = (p & 0x80000000u) ? (p & 0x7fffffffu) : ~p;
  return __uint_as_float(u);
}
static __device__ __forceinline__ unsigned long long pk64(float s, int idx) {
  return ((unsigned long long)pk32(s) << 32) | (unsigned)idx;
}
static __device__ __forceinline__ unsigned short bf16rne(float f) {
  unsigned u = __float_as_uint(f);
  unsigned r = u + 0x7fffu + ((u >> 16) & 1u);
  return (unsigned short)(r >> 16);
}
static __device__ __forceinline__ void gld16(const void* g, void* l) {
  __builtin_amdgcn_global_load_lds(
      (const __attribute__((address_space(1))) unsigned int*)g,
      (__attribute__((address_space(3))) unsigned int*)l, 16, 0, 0);
}
// insert x into sorted triple (b,s,t)
static __device__ __forceinline__ void mrg3(unsigned& b, unsigned& s, unsigned& t, unsigned x) {
  if (x < b) { t = s; s = b; b = x; }
  else if (x < s) { t = s; s = x; }
  else if (x < t) { t = x; }
}
// exact fp32 score key for code cidx vs LDS-staged z row (k-order fmaf chain,
// identical arithmetic to the round-1-verified scalar version; float4 loads)
static __device__ __forceinline__ unsigned long long exdot(const float* __restrict__ emb,
                                                           const float* zr, float z2t,
                                                           const float* __restrict__ e2,
                                                           int cidx) {
  {
    #pragma clang fp contract(off)
    const float* er = emb + (size_t)cidx * DIM;
    float m = 0.0f;
    #pragma unroll 8
    for (int k4 = 0; k4 < DIM / 4; k4++) {
      float4 v = reinterpret_cast<const float4*>(er)[k4];
      m = fmaf(2.0f * zr[4 * k4 + 0], v.x, m);
      m = fmaf(2.0f * zr[4 * k4 + 1], v.y, m);
      m = fmaf(2.0f * zr[4 * k4 + 2], v.z, m);
      m = fmaf(2.0f * zr[4 * k4 + 3], v.w, m);
    }
    float sc = (z2t - m) + e2[cidx];
    return pk64(sc, cidx);
  }
}

// ---------------- K1: prep (z2/e2 pairwise-exact, zb/eb bf16 copies, inits) --
__global__ __launch_bounds__(256) void vq_prep(const float* __restrict__ z,
                                               const float* __restrict__ emb,
                                               float* __restrict__ e2,
                                               float* __restrict__ z2,
                                               unsigned* __restrict__ q0,
                                               unsigned* __restrict__ q1,
                                               unsigned* __restrict__ q2,
                                               unsigned* __restrict__ work,
                                               unsigned short* __restrict__ zb,
                                               unsigned short* __restrict__ eb,
                                               float* __restrict__ loss_slot) {
  int gid = blockIdx.x * 256 + threadIdx.x;
  if (gid < NTOK) {
    #pragma unroll
    for (int g = 0; g < NGRP; g++) {
      q0[(size_t)g * NTOK + gid] = 0xFFFFFFFFu;
      q1[(size_t)g * NTOK + gid] = 0xFFFFFFFFu;
      q2[(size_t)g * NTOK + gid] = 0xFFFFFFFFu;
    }
  }
  if (gid == 0) { loss_slot[0] = 0.0f; work[0] = 0u; }

  int wave = gid >> 6;
  int lane = threadIdx.x & 63;
  int row = wave * 16 + (lane >> 2);            // 0..40959
  int sub = lane & 3;
  int q = sub & 1, h = sub >> 1;

  const float* src = (row < NTOK) ? (z + (size_t)row * DIM)
                                  : (emb + (size_t)(row - NTOK) * DIM);
  unsigned short* dst = (row < NTOK) ? (zb + (size_t)row * DIM)
                                     : (eb + (size_t)(row - NTOK) * DIM);
  const float4* p = reinterpret_cast<const float4*>(src + h * 128 + q * 4);

  float r0, r1, r2, r3, s;
  {
    #pragma clang fp contract(off)
    r0 = 0.0f; r1 = 0.0f; r2 = 0.0f; r3 = 0.0f;
    #pragma unroll
    for (int t = 0; t < 16; t++) {
      float4 v = p[2 * t];
      ushort4 w;
      w.x = bf16rne(v.x); w.y = bf16rne(v.y); w.z = bf16rne(v.z); w.w = bf16rne(v.w);
      *reinterpret_cast<ushort4*>(dst + h * 128 + q * 4 + t * 8) = w;
      float q0f = v.x * v.x, q1f = v.y * v.y, q2f = v.z * v.z, q3f = v.w * v.w;
      r0 = r0 + q0f; r1 = r1 + q1f; r2 = r2 + q2f; r3 = r3 + q3f;
    }
    s = (r0 + r1) + (r2 + r3);
    s = s + __shfl_xor(s, 1, 64);
    s = s + __shfl_xor(s, 2, 64);
  }
  if (sub == 0) {
    if (row < NTOK) z2[row] = s;
    else            e2[row - NTOK] = s;
  }
}

// ---------------- K2: single-pass bf16 MFMA scoring --------------------------
// Main loop = round-1 verified structure: BOTH operands via global_load_lds
// from precomputed bf16 (zb, eb), BK=64, XOR-swizzled.  Epilogue: per-token
// TOP-3 within the block's 128 codes (round-7 lesson: top-2 per 1024-group
// made 2-in-band-same-group a 1MB scan, P~0.07/token -> 1.67GB chain fetch;
// top-3 stores the 2nd AND 3rd with columns, so scans need 3-in-band-same-
// group, ~25x rarer).  Group top-3 maintained exactly by the lock-free
// atomicMin displacement cascade: o=atomicMin(Q0,x); d=max(x,o);
// o=atomicMin(Q1,d); d=max(d,o); atomicMin(Q2,d).  Each block submits its
// top-3 so the group's true top-3 are always among submissions.
__global__ __launch_bounds__(256, 2) void vq_score(const unsigned short* __restrict__ zb,
                                                   const unsigned short* __restrict__ eb,
                                                   unsigned* __restrict__ q0,
                                                   unsigned* __restrict__ q1,
                                                   unsigned* __restrict__ q2,
                                                   const float* __restrict__ e2) {
  __shared__ unsigned short Ab[128 * 64];
  __shared__ unsigned short Bb[128 * 64];
  __shared__ unsigned sbuf[128][8];
  __shared__ unsigned ssec[128][8];
  __shared__ unsigned sthr[128][8];

  const int tid = threadIdx.x;
  const int t0 = blockIdx.y * 128;
  const int e0 = blockIdx.x * 128;
  const int lane = tid & 63;
  const int wv = tid >> 6;
  const int wm = wv & 1, wn = wv >> 1;

  f32x4 acc[4][4];
  #pragma unroll
  for (int i = 0; i < 4; i++)
    #pragma unroll
    for (int j = 0; j < 4; j++) acc[i][j] = (f32x4)0.0f;

  // staging: phys slot s of row r holds logical k-slot s^(r&7); gld16 writes
  // linearly so the swizzle is applied on the GLOBAL source address.
  const int r0 = tid >> 3;
  const int sq = (tid & 7) ^ (r0 & 7);
  const size_t ga = (size_t)(t0 + r0) * DIM + sq * 8;
  const size_t gb = (size_t)(e0 + r0) * DIM + sq * 8;
  char* la0 = (char*)Ab + tid * 16;
  char* lb0 = (char*)Bb + tid * 16;

  // fragment reads: row = w*64 + f*16 + la  ->  row&7 == la&7 (loop-invariant)
  const int la = lane & 15, lq = lane >> 4;
  const int key = la & 7;
  const char* Abase = (const char*)Ab + (wm * 64 + la) * 128;
  const char* Bbase = (const char*)Bb + (wn * 64 + la) * 128;

  for (int kc = 0; kc < DIM; kc += 64) {
    __syncthreads();
    #pragma unroll
    for (int i = 0; i < 4; i++) {
      gld16(zb + ga + kc + (size_t)(i * 32) * DIM, la0 + i * 4096);
      gld16(eb + gb + kc + (size_t)(i * 32) * DIM, lb0 + i * 4096);
    }
    __syncthreads();
    #pragma unroll
    for (int ks = 0; ks < 2; ks++) {
      const int q = ((ks * 4 + lq) ^ key) * 16;
      short8 a[4], b[4];
      #pragma unroll
      for (int f = 0; f < 4; f++) {
        a[f] = *reinterpret_cast<const short8*>(Abase + f * 2048 + q);
        b[f] = *reinterpret_cast<const short8*>(Bbase + f * 2048 + q);
      }
      #pragma unroll
      for (int fi = 0; fi < 4; fi++)
        #pragma unroll
        for (int fj = 0; fj < 4; fj++)
          acc[fi][fj] = __builtin_amdgcn_mfma_f32_16x16x32_bf16(a[fi], b[fj], acc[fi][fj], 0, 0, 0);
    }
  }

  float e2c[4];
  #pragma unroll
  for (int fj = 0; fj < 4; fj++)
    e2c[fj] = e2[e0 + wn * 64 + fj * 16 + la];

  // ---- epilogue: per-token top-3 within this 128-wide e-tile ----
  const unsigned colbase = (unsigned)(wn * 64 + la);
  #pragma unroll
  for (int fi = 0; fi < 4; fi++) {
    #pragma unroll
    for (int r = 0; r < 4; r++) {
      unsigned b = 0xFFFFFFFFu, s2 = 0xFFFFFFFFu, t3 = 0xFFFFFFFFu;
      #pragma unroll
      for (int fj = 0; fj < 4; fj++) {
        float sc = fmaf(-2.0f, acc[fi][fj][r], e2c[fj]);
        unsigned e = ((pk32(sc) >> 13) << 7) | (colbase + (unsigned)(fj * 16));
        mrg3(b, s2, t3, e);
      }
      #pragma unroll
      for (int off = 1; off < 4; off <<= 1) {
        unsigned ob = __shfl_xor(b, off, 64);
        unsigned os = __shfl_xor(s2, off, 64);
        unsigned ot = __shfl_xor(t3, off, 64);
        mrg3(b, s2, t3, ob); mrg3(b, s2, t3, os); mrg3(b, s2, t3, ot);
      }
      if ((la & 3) == 0) {
        int tl = wm * 64 + fi * 16 + (lq << 2) + r;
        int slot = wn * 4 + (la >> 2);
        sbuf[tl][slot] = b;
        ssec[tl][slot] = s2;
        sthr[tl][slot] = t3;
      }
    }
  }
  __syncthreads();
  if (tid < 128) {
    unsigned B = 0xFFFFFFFFu, S = 0xFFFFFFFFu, T = 0xFFFFFFFFu;
    #pragma unroll
    for (int p = 0; p < 8; p++) {
      mrg3(B, S, T, sbuf[tid][p]);
      mrg3(B, S, T, ssec[tid][p]);
      mrg3(B, S, T, sthr[tid][p]);
    }
    const int t = t0 + tid;
    const int grp = e0 >> 10;
    const unsigned cb = (unsigned)(e0 & 1023);
    unsigned* Q0 = &q0[(size_t)grp * NTOK + t];
    unsigned* Q1 = &q1[(size_t)grp * NTOK + t];
    unsigned* Q2 = &q2[(size_t)grp * NTOK + t];
    unsigned xs[3];
    xs[0] = ((B >> 7) << 10) | (cb + (B & 127u));
    xs[1] = ((S >> 7) << 10) | (cb + (S & 127u));
    xs[2] = ((T >> 7) << 10) | (cb + (T & 127u));
    #pragma unroll
    for (int i = 0; i < 3; i++) {
      unsigned x = xs[i];
      unsigned o0 = atomicMin(Q0, x);
      unsigned d0 = x > o0 ? x : o0;
      unsigned o1 = atomicMin(Q1, d0);
      unsigned d1 = d0 > o1 ? d0 : o1;
      atomicMin(Q2, d1);
    }
  }
}

// ---------------- K3a: derive global top-2 from group top-3; build masks -----
// Global best = min over q0[g]; global second = min(2nd-smallest q0, q1 of the
// best group).  Ambiguous tokens emit {token, mask}: bits 0..7 = q0 in band,
// 8..15 = q1 in band, 16..23 = q2 in band (-> exact-scan that 1024-code group,
// since rank>=4 codes of that group could also be in band).
__global__ __launch_bounds__(256) void vq_reduce(const unsigned* __restrict__ q0,
                                                 const unsigned* __restrict__ q1,
                                                 const unsigned* __restrict__ q2,
                                                 unsigned* __restrict__ winners,
                                                 unsigned* __restrict__ work,
                                                 unsigned* __restrict__ cmask) {
  int t = blockIdx.x * 256 + threadIdx.x;
  unsigned v0[NGRP];
  unsigned b = 0xFFFFFFFFu, s = 0xFFFFFFFFu;
  int bg = 0;
  #pragma unroll
  for (int g = 0; g < NGRP; g++) {
    v0[g] = q0[(size_t)g * NTOK + t];
    if (v0[g] < b) { s = b; b = v0[g]; bg = g; }
    else if (v0[g] < s) { s = v0[g]; }
  }
  unsigned q1b = q1[(size_t)bg * NTOK + t];
  s = q1b < s ? q1b : s;
  float fb = upk32((b >> 10) << 13);
  float fs = upk32((s >> 10) << 13);
  if (fs > fb + DSELQ) { winners[t] = (unsigned)(bg * 1024) + (b & 1023u); return; }

  unsigned bk = pk32(fb + EPSF) >> 13;
  unsigned m = 0;
  #pragma unroll
  for (int g = 0; g < NGRP; g++) {
    if ((v0[g] >> 10) <= bk)                          m |= 1u << g;
    if ((q1[(size_t)g * NTOK + t] >> 10) <= bk)       m |= 1u << (8 + g);
    if ((q2[(size_t)g * NTOK + t] >> 10) <= bk)       m |= 1u << (16 + g);
  }
  unsigned w = atomicAdd(&work[0], 1u);
  work[1 + w] = (unsigned)t;
  cmask[w] = m;
}

// ---------------- K3b: exact fp32 resolution for ambiguous tokens ------------
// One wave per token.  Lanes 0-7/8-15/16-23 exdot the q0/q1/q2 entries of
// groups whose respective level is in band (skipped if the group is scanned).
// Groups whose q2 is in band are exact-scanned (1024 codes, 16 rounds) --
// covers any hidden rank>=4 candidate.  Completeness: a hidden code's key >=
// its group's q2 key, so "q2 key > bandkey" proves no hidden in-band code.
__global__ __launch_bounds__(64) void vq_chain(const float* __restrict__ z,
                                               const float* __restrict__ emb,
                                               const float* __restrict__ z2,
                                               const float* __restrict__ e2,
                                               const unsigned* __restrict__ q0,
                                               const unsigned* __restrict__ q1,
                                               const unsigned* __restrict__ q2,
                                               const unsigned* __restrict__ work,
                                               const unsigned* __restrict__ cmask,
                                               unsigned* __restrict__ winners) {
  __shared__ float zr[256];
  const int lane = threadIdx.x;
  const int nw = (int)work[0];

  for (int i = blockIdx.x; i < nw; i += gridDim.x) {
    int t = (int)work[1 + i];
    float4 zv = reinterpret_cast<const float4*>(z + (size_t)t * DIM)[lane];
    *reinterpret_cast<float4*>(&zr[lane * 4]) = zv;
    __syncthreads();
    const float z2t = z2[t];
    const unsigned m = cmask[i];
    const unsigned scanm = (m >> 16) & 0xFFu;

    unsigned long long best = ~0ull;
    if (lane < 24) {
      int lvl = lane >> 3;
      int g = lane & 7;
      bool on = (m >> (lvl * 8 + g)) & 1u;
      if (on && !((scanm >> g) & 1u)) {
        const unsigned* Q = (lvl == 0) ? q0 : ((lvl == 1) ? q1 : q2);
        unsigned e = Q[(size_t)g * NTOK + t];
        int cidx = g * 1024 + (int)(e & 1023u);
        best = exdot(emb, zr, z2t, e2, cidx);
      }
    }
    unsigned sc = scanm;
    while (sc) {
      int g = __ffs(sc) - 1;
      sc &= sc - 1;
      for (int r = 0; r < 16; r++) {
        int cidx = g * 1024 + r * 64 + lane;
        unsigned long long kk = exdot(emb, zr, z2t, e2, cidx);
        best = kk < best ? kk : best;
      }
    }
    #pragma unroll
    for (int off = 32; off > 0; off >>= 1) {
      unsigned long long o = __shfl_xor(best, off, 64);
      best = o < best ? o : best;
    }
    if (lane == 0) winners[t] = (unsigned)(best & 0xffffffffu);
    __syncthreads();
  }
}

// ---------------- K4: gather zq = emb[winner], idx, loss ---------------------
__global__ __launch_bounds__(256) void vq_emit(const float* __restrict__ z,
                                               const float* __restrict__ emb,
                                               const unsigned* __restrict__ winners,
                                               float* __restrict__ out_zq,
                                               float* __restrict__ out_loss,
                                               float* __restrict__ out_idx) {
  __shared__ float lsum[4];
  const int wid = threadIdx.x >> 6;
  const int lane = threadIdx.x & 63;
  const int tbase = blockIdx.x * 16 + wid * 4;
  float s_acc = 0.0f;
  #pragma unroll
  for (int it = 0; it < 4; it++) {
    int t = tbase + it;
    unsigned idx = winners[t];
    float4 e = reinterpret_cast<const float4*>(emb + (size_t)idx * DIM)[lane];
    float4 zz = reinterpret_cast<const float4*>(z + (size_t)t * DIM)[lane];
    reinterpret_cast<float4*>(out_zq + (size_t)t * DIM)[lane] = e;
    float dx = e.x - zz.x, dy = e.y - zz.y, dz = e.z - zz.z, dw = e.w - zz.w;
    s_acc += dx * dx + dy * dy + dz * dz + dw * dw;
    if (lane == 0) out_idx[t] = (float)idx;
  }
  #pragma unroll
  for (int off = 32; off > 0; off >>= 1) s_acc += __shfl_down(s_acc, off, 64);
  if (lane == 0) lsum[wid] = s_acc;
  __syncthreads();
  if (threadIdx.x == 0) {
    float tot = (lsum[0] + lsum[1] + lsum[2] + lsum[3]) * (1.25f / 8388608.0f);
    atomicAdd(out_loss, tot);
  }
}

// ====================== round-3 verified fallback path =======================
#define BT 128
#define BE 128
#define BK 32
#define LDW 132

__global__ __launch_bounds__(256) void fb_init(const float* __restrict__ z,
                                               const float* __restrict__ emb,
                                               float* __restrict__ e2,
                                               float* __restrict__ z2,
                                               unsigned long long* __restrict__ k1,
                                               float* __restrict__ loss_slot) {
  int gid = blockIdx.x * 256 + threadIdx.x;
  if (gid < NTOK) k1[gid] = ~0ull;
  if (gid == 0) loss_slot[0] = 0.0f;
  int wave = gid >> 6;
  int lane = threadIdx.x & 63;
  int row = wave * 16 + (lane >> 2);
  int sub = lane & 3;
  int q = sub & 1, h = sub >> 1;
  const float* src = (row < NTOK) ? (z + (size_t)row * DIM)
                                  : (emb + (size_t)(row - NTOK) * DIM);
  const float4* p = reinterpret_cast<const float4*>(src + h * 128 + q * 4);
  float r0, r1, r2, r3, s;
  {
    #pragma clang fp contract(off)
    r0 = 0.0f; r1 = 0.0f; r2 = 0.0f; r3 = 0.0f;
    #pragma unroll
    for (int t = 0; t < 16; t++) {
      float4 v = p[2 * t];
      float q0 = v.x * v.x, q1 = v.y * v.y, q2 = v.z * v.z, q3 = v.w * v.w;
      r0 = r0 + q0; r1 = r1 + q1; r2 = r2 + q2; r3 = r3 + q3;
    }
    s = (r0 + r1) + (r2 + r3);
    s = s + __shfl_xor(s, 1, 64);
    s = s + __shfl_xor(s, 2, 64);
  }
  if (sub == 0) {
    if (row < NTOK) z2[row] = s;
    else            e2[row - NTOK] = s;
  }
}

__global__ __launch_bounds__(256, 4) void fb_score(const float* __restrict__ z,
                                                   const float* __restrict__ emb,
                                                   const float* __restrict__ e2,
                                                   const float* __restrict__ z2,
                                                   unsigned long long* __restrict__ k1) {
  __shared__ float As[BK][LDW];
  __shared__ float Bs[BK][LDW];
  __shared__ unsigned long long mkey[BT];
  const int tid = threadIdx.x;
  const int t0 = blockIdx.x * BT;
  const int e0 = blockIdx.y * BE;
  const int tx = tid & 15;
  const int ty = tid >> 4;
  if (tid < BT) mkey[tid] = ~0ull;
  float acc[8][8];
  #pragma unroll
  for (int i = 0; i < 8; i++)
    #pragma unroll
    for (int j = 0; j < 8; j++) acc[i][j] = 0.0f;
  const float* __restrict__ zt = z + (size_t)t0 * DIM;
  const float* __restrict__ et = emb + (size_t)e0 * DIM;
  for (int kc = 0; kc < DIM; kc += BK) {
    __syncthreads();
    #pragma unroll
    for (int i = 0; i < 4; i++) {
      int f = tid + i * 256;
      int row = f >> 3;
      int kq = f & 7;
      const float4 va = *reinterpret_cast<const float4*>(zt + row * DIM + kc + kq * 4);
      const float4 vb = *reinterpret_cast<const float4*>(et + row * DIM + kc + kq * 4);
      int k = kq * 4;
      As[k + 0][row] = va.x * 2.0f; As[k + 1][row] = va.y * 2.0f;
      As[k + 2][row] = va.z * 2.0f; As[k + 3][row] = va.w * 2.0f;
      Bs[k + 0][row] = vb.x; Bs[k + 1][row] = vb.y;
      Bs[k + 2][row] = vb.z; Bs[k + 3][row] = vb.w;
    }
    __syncthreads();
    #pragma unroll 4
    for (int k = 0; k < BK; k++) {
      float a[8], b[8];
      *(float4*)&a[0] = *(const float4*)&As[k][ty * 8];
      *(float4*)&a[4] = *(const float4*)&As[k][ty * 8 + 4];
      *(float4*)&b[0] = *(const float4*)&Bs[k][tx * 8];
      *(float4*)&b[4] = *(const float4*)&Bs[k][tx * 8 + 4];
      #pragma unroll
      for (int i = 0; i < 8; i++)
        #pragma unroll
        for (int j = 0; j < 8; j++)
          acc[i][j] = fmaf(a[i], b[j], acc[i][j]);
    }
  }
  float e2c[8], z2t[8];
  *(float4*)&e2c[0] = *(const float4*)(e2 + e0 + tx * 8);
  *(float4*)&e2c[4] = *(const float4*)(e2 + e0 + tx * 8 + 4);
  *(float4*)&z2t[0] = *(const float4*)(z2 + t0 + ty * 8);
  *(float4*)&z2t[4] = *(const float4*)(z2 + t0 + ty * 8 + 4);
  {
    #pragma clang fp contract(off)
    #pragma unroll
    for (int i = 0; i < 8; i++) {
      int trow = ty * 8 + i;
      unsigned long long best = ~0ull;
      #pragma unroll
      for (int j = 0; j < 8; j++) {
        float t1 = z2t[i] - acc[i][j];
        float s = t1 + e2c[j];
        unsigned long long kk = pk64(s, e0 + tx * 8 + j);
        best = kk < best ? kk : best;
      }
      atomicMin(&mkey[trow], best);
    }
  }
  __syncthreads();
  if (tid < BT) atomicMin(&k1[t0 + tid], mkey[tid]);
}

__global__ __launch_bounds__(256) void fb_out(const float* __restrict__ z,
                                              const float* __restrict__ emb,
                                              const unsigned long long* __restrict__ k1,
                                              float* __restrict__ out_zq,
                                              float* __restrict__ out_loss,
                                              float* __restrict__ out_idx) {
  __shared__ float lsum[4];
  const int wid = threadIdx.x >> 6;
  const int lane = threadIdx.x & 63;
  const int tbase = blockIdx.x * 16 + wid * 4;
  float s_acc = 0.0f;
  #pragma unroll
  for (int it = 0; it < 4; it++) {
    int t = tbase + it;
    unsigned idx = (unsigned)(k1[t] & 0xffffffffu);
    float4 e = reinterpret_cast<const float4*>(emb + (size_t)idx * DIM)[lane];
    float4 zz = reinterpret_cast<const float4*>(z + (size_t)t * DIM)[lane];
    reinterpret_cast<float4*>(out_zq + (size_t)t * DIM)[lane] = e;
    float dx = e.x - zz.x, dy = e.y - zz.y, dz = e.z - zz.z, dw = e.w - zz.w;
    s_acc += dx * dx + dy * dy + dz * dz + dw * dw;
    if (lane == 0) out_idx[t] = (float)idx;
  }
  #pragma unroll
  for (int off = 32; off > 0; off >>= 1) s_acc += __shfl_down(s_acc, off, 64);
  if (lane == 0) lsum[wid] = s_acc;
  __syncthreads();
  if (threadIdx.x == 0) {
    float tot = (lsum[0] + lsum[1] + lsum[2] + lsum[3]) * (1.25f / 8388608.0f);
    atomicAdd(out_loss, tot);
  }
}

// ============================== launcher =====================================
extern "C" void kernel_launch(void* const* d_in, const int* in_sizes, int n_in,
                              void* d_out, int out_size, void* d_ws, size_t ws_size,
                              hipStream_t stream) {
  const float* z = (const float*)d_in[0];
  const float* emb = (const float*)d_in[1];
  float* out = (float*)d_out;
  float* out_zq = out;
  float* out_loss = out + (size_t)NTOK * DIM;
  float* out_idx = out_loss + 1;

  // ws: e2 | z2 | q0[8][NTOK] | q1 | q2 | work | cmask | winners | zb | eb
  const size_t OFF_Z2   = 32768;
  const size_t OFF_Q0   = 163840;
  const size_t OFF_Q1   = OFF_Q0 + (size_t)NGRP * NTOK * 4;    // 1212416
  const size_t OFF_Q2   = OFF_Q1 + (size_t)NGRP * NTOK * 4;    // 2260992
  const size_t OFF_WORK = OFF_Q2 + (size_t)NGRP * NTOK * 4;    // 3309568
  const size_t OFF_CM   = (OFF_WORK + 4 + 4 * (size_t)NTOK + 15) & ~(size_t)15; // 3440656
  const size_t OFF_WIN  = OFF_CM + 4 * (size_t)NTOK;           // 3571728
  const size_t OFF_ZB   = OFF_WIN + 4 * (size_t)NTOK;          // 3702800
  const size_t OFF_EB   = OFF_ZB + (size_t)NTOK * DIM * 2;     // 20480016
  const size_t REQ      = OFF_EB + (size_t)NE * DIM * 2;       // 24674320

  if (ws_size >= REQ) {
    float* e2 = (float*)d_ws;
    float* z2 = (float*)((char*)d_ws + OFF_Z2);
    unsigned* q0 = (unsigned*)((char*)d_ws + OFF_Q0);
    unsigned* q1 = (unsigned*)((char*)d_ws + OFF_Q1);
    unsigned* q2 = (unsigned*)((char*)d_ws + OFF_Q2);
    unsigned* work = (unsigned*)((char*)d_ws + OFF_WORK);
    unsigned* cmask = (unsigned*)((char*)d_ws + OFF_CM);
    unsigned* winners = (unsigned*)((char*)d_ws + OFF_WIN);
    unsigned short* zb = (unsigned short*)((char*)d_ws + OFF_ZB);
    unsigned short* eb = (unsigned short*)((char*)d_ws + OFF_EB);

    hipLaunchKernelGGL(vq_prep, dim3(640), dim3(256), 0, stream,
                       z, emb, e2, z2, q0, q1, q2, work, zb, eb, out_loss);
    hipLaunchKernelGGL(vq_score, dim3(NE / 128, NTOK / 128), dim3(256), 0, stream,
                       zb, eb, q0, q1, q2, e2);
    hipLaunchKernelGGL(vq_reduce, dim3(NTOK / 256), dim3(256), 0, stream,
                       q0, q1, q2, winners, work, cmask);
    hipLaunchKernelGGL(vq_chain, dim3(4096), dim3(64), 0, stream,
                       z, emb, z2, e2, q0, q1, q2, work, cmask, winners);
    hipLaunchKernelGGL(vq_emit, dim3(NTOK / 16), dim3(256), 0, stream,
                       z, emb, winners, out_zq, out_loss, out_idx);
  } else {
    float* e2 = (float*)d_ws;
    float* z2 = (float*)((char*)d_ws + 32768);
    unsigned long long* k1 = (unsigned long long*)((char*)d_ws + 262144);
    hipLaunchKernelGGL(fb_init, dim3(640), dim3(256), 0, stream,
                       z, emb, e2, z2, k1, out_loss);
    hipLaunchKernelGGL(fb_score, dim3(NTOK / BT, NE / BE), dim3(256), 0, stream,
                       z, emb, e2, z2, k1);
    hipLaunchKernelGGL(fb_out, dim3(NTOK / 16), dim3(256), 0, stream,
                       z, emb, k1, out_zq, out_loss, out_idx);
  }
}

// Round 9
// 1832.411 us; speedup vs baseline: 1.2414x; 1.2414x over previous
//
#include <hip/hip_runtime.h>

#define NTOK  32768
#define NE    8192
#define DIM   256
#define NGRP  8        // 1024 codes per group
#define EPSF  5.0e-4f   // candidate band slack (>= 2*delta bound 3.2e-4 + key quantum)
#define DSELQ 4.8e-4f   // ambiguity bound on quantized keys (4.5e-4 + quantum slop)

typedef __attribute__((ext_vector_type(8))) short short8;
typedef __attribute__((ext_vector_type(4))) float f32x4;

static __device__ __forceinline__ unsigned pk32(float f) {
  unsigned u = __float_as_uint(f);
  return (u & 0x80000000u) ? ~u : (u | 0x80000000u);
}
static __device__ __forceinline__ float upk32(unsigned p) {
  unsigned u = (p & 0x80000000u) ? (p & 0x7fffffffu) : ~p;
  return __uint_as_float(u);
}
static __device__ __forceinline__ unsigned long long pk64(float s, int idx) {
  return ((unsigned long long)pk32(s) << 32) | (unsigned)idx;
}
static __device__ __forceinline__ unsigned short bf16rne(float f) {
  unsigned u = __float_as_uint(f);
  unsigned r = u + 0x7fffu + ((u >> 16) & 1u);
  return (unsigned short)(r >> 16);
}
static __device__ __forceinline__ void gld16(const void* g, void* l) {
  __builtin_amdgcn_global_load_lds(
      (const __attribute__((address_space(1))) unsigned int*)g,
      (__attribute__((address_space(3))) unsigned int*)l, 16, 0, 0);
}
// insert x into sorted triple (b,s,t)
static __device__ __forceinline__ void mrg3(unsigned& b, unsigned& s, unsigned& t, unsigned x) {
  if (x < b) { t = s; s = b; b = x; }
  else if (x < s) { t = s; s = x; }
  else if (x < t) { t = x; }
}
// exact fp32 score key for code cidx vs LDS-staged z row (k-order fmaf chain,
// identical arithmetic to the round-1-verified scalar version; float4 loads)
static __device__ __forceinline__ unsigned long long exdot(const float* __restrict__ emb,
                                                           const float* zr, float z2t,
                                                           const float* __restrict__ e2,
                                                           int cidx) {
  {
    #pragma clang fp contract(off)
    const float* er = emb + (size_t)cidx * DIM;
    float m = 0.0f;
    #pragma unroll 8
    for (int k4 = 0; k4 < DIM / 4; k4++) {
      float4 v = reinterpret_cast<const float4*>(er)[k4];
      m = fmaf(2.0f * zr[4 * k4 + 0], v.x, m);
      m = fmaf(2.0f * zr[4 * k4 + 1], v.y, m);
      m = fmaf(2.0f * zr[4 * k4 + 2], v.z, m);
      m = fmaf(2.0f * zr[4 * k4 + 3], v.w, m);
    }
    float sc = (z2t - m) + e2[cidx];
    return pk64(sc, cidx);
  }
}

// ---------------- K1: prep (z2/e2 pairwise-exact, zb/eb bf16 copies, inits) --
__global__ __launch_bounds__(256) void vq_prep(const float* __restrict__ z,
                                               const float* __restrict__ emb,
                                               float* __restrict__ e2,
                                               float* __restrict__ z2,
                                               unsigned* __restrict__ work,
                                               unsigned short* __restrict__ zb,
                                               unsigned short* __restrict__ eb,
                                               float* __restrict__ loss_slot) {
  int gid = blockIdx.x * 256 + threadIdx.x;
  if (gid == 0) { loss_slot[0] = 0.0f; work[0] = 0u; }

  int wave = gid >> 6;
  int lane = threadIdx.x & 63;
  int row = wave * 16 + (lane >> 2);            // 0..40959
  int sub = lane & 3;
  int q = sub & 1, h = sub >> 1;

  const float* src = (row < NTOK) ? (z + (size_t)row * DIM)
                                  : (emb + (size_t)(row - NTOK) * DIM);
  unsigned short* dst = (row < NTOK) ? (zb + (size_t)row * DIM)
                                     : (eb + (size_t)(row - NTOK) * DIM);
  const float4* p = reinterpret_cast<const float4*>(src + h * 128 + q * 4);

  float r0, r1, r2, r3, s;
  {
    #pragma clang fp contract(off)
    r0 = 0.0f; r1 = 0.0f; r2 = 0.0f; r3 = 0.0f;
    #pragma unroll
    for (int t = 0; t < 16; t++) {
      float4 v = p[2 * t];
      ushort4 w;
      w.x = bf16rne(v.x); w.y = bf16rne(v.y); w.z = bf16rne(v.z); w.w = bf16rne(v.w);
      *reinterpret_cast<ushort4*>(dst + h * 128 + q * 4 + t * 8) = w;
      float q0f = v.x * v.x, q1f = v.y * v.y, q2f = v.z * v.z, q3f = v.w * v.w;
      r0 = r0 + q0f; r1 = r1 + q1f; r2 = r2 + q2f; r3 = r3 + q3f;
    }
    s = (r0 + r1) + (r2 + r3);
    s = s + __shfl_xor(s, 1, 64);
    s = s + __shfl_xor(s, 2, 64);
  }
  if (sub == 0) {
    if (row < NTOK) z2[row] = s;
    else            e2[row - NTOK] = s;
  }
}

// ---------------- K2: single-pass bf16 MFMA scoring, 1024-code group/block ---
// Round-8 lesson: 9-deep chained device-atomic cascades made the epilogue a
// latency disaster (1768us, MfmaUtil 3.2%).  Fix: ONE block owns a whole
// 1024-code group -> group top-3 computed locally, written with PLAIN stores.
// A tile (128 tok x 256 dims bf16, 64KB) stays LDS-resident for all 8
// e-subtiles (8x A reuse); only the 16KB B chunk is staged per K-step (half
// of round-1's per-chunk staging).  Same XOR swizzle (low-3 slot bits), same
// verified gld16 path for both operands.  Grid (8,256): group g -> XCD g, so
// each group's 512KB eb slab is permanently L2-resident on its XCD.
__global__ __launch_bounds__(256, 2) void vq_score(const unsigned short* __restrict__ zb,
                                                   const unsigned short* __restrict__ eb,
                                                   unsigned* __restrict__ q0,
                                                   unsigned* __restrict__ q1,
                                                   unsigned* __restrict__ q2,
                                                   const float* __restrict__ e2) {
  __shared__ unsigned short Ab[128 * 256];   // 64KB resident A tile (swizzled)
  __shared__ unsigned short Bb[128 * 64];    // 16KB B chunk; aliased as merge buf after loop

  const int tid = threadIdx.x;
  const int g  = blockIdx.x;                 // code group (1024 codes)
  const int t0 = blockIdx.y * 128;
  const int lane = tid & 63;
  const int wv = tid >> 6;
  const int wm = wv & 1, wn = wv >> 1;

  // ---- stage full A tile once: phys 16B-slot s of row r holds logical slot
  //      (s&~7)|((s&7)^(r&7)); gld16 writes linearly -> swizzle on global src.
  {
    const int r = tid >> 5;                  // base row 0..7 (+8 per round)
    const int s = tid & 31;                  // slot 0..31
    const int k = r & 7;                     // (r+8i)&7 == r&7: loop-invariant
    const size_t gsrc = (size_t)(t0 + r) * DIM + (size_t)(((s & 24) | ((s & 7) ^ k)) * 8);
    char* ld = (char*)Ab + tid * 16;
    #pragma unroll
    for (int i = 0; i < 16; i++)
      gld16(zb + gsrc + (size_t)(i * 8) * DIM, ld + i * 4096);
  }

  f32x4 acc[4][4];
  #pragma unroll
  for (int i = 0; i < 4; i++)
    #pragma unroll
    for (int j = 0; j < 4; j++) acc[i][j] = (f32x4)0.0f;

  unsigned top3[4][4][3];
  #pragma unroll
  for (int i = 0; i < 4; i++)
    #pragma unroll
    for (int j = 0; j < 4; j++) {
      top3[i][j][0] = 0xFFFFFFFFu; top3[i][j][1] = 0xFFFFFFFFu; top3[i][j][2] = 0xFFFFFFFFu;
    }

  // B staging geometry (per chunk): row br+32i, slot bs holds logical bs^(br&7)
  const int br = tid >> 3;
  const int bs = tid & 7;
  const int bkey = br & 7;
  char* lb0 = (char*)Bb + tid * 16;

  // fragment read geometry
  const int la = lane & 15, lq = lane >> 4;
  const int key = la & 7;
  const char* Abase = (const char*)Ab + (wm * 64 + la) * 512;
  const char* Bbase = (const char*)Bb + (wn * 64 + la) * 128;

  for (int es = 0; es < 8; es++) {
    for (int kc = 0; kc < DIM; kc += 64) {
      __syncthreads();   // Bb safe to overwrite; also drains A-stage on iter 0
      #pragma unroll
      for (int i = 0; i < 4; i++)
        gld16(eb + (size_t)(g * 1024 + es * 128 + br + i * 32) * DIM + kc + (bs ^ bkey) * 8,
              lb0 + i * 4096);
      __syncthreads();
      #pragma unroll
      for (int ks = 0; ks < 2; ks++) {
        const int qa = (kc >> 3) + ((ks * 4 + lq) ^ key);   // A phys slot (0..31)
        const int qb = (ks * 4 + lq) ^ key;                 // B phys slot (0..7)
        short8 a[4], b[4];
        #pragma unroll
        for (int f = 0; f < 4; f++) {
          a[f] = *reinterpret_cast<const short8*>(Abase + f * 16 * 512 + qa * 16);
          b[f] = *reinterpret_cast<const short8*>(Bbase + f * 2048 + qb * 16);
        }
        #pragma unroll
        for (int fi = 0; fi < 4; fi++)
          #pragma unroll
          for (int fj = 0; fj < 4; fj++)
            acc[fi][fj] = __builtin_amdgcn_mfma_f32_16x16x32_bf16(a[fi], b[fj], acc[fi][fj], 0, 0, 0);
      }
    }
    // ---- fold subtile es into register top-3 (entry = key19<<10 | col10) ----
    float e2c[4];
    #pragma unroll
    for (int fj = 0; fj < 4; fj++)
      e2c[fj] = e2[g * 1024 + es * 128 + wn * 64 + fj * 16 + la];
    const unsigned colbase = (unsigned)(es * 128 + wn * 64 + la);
    #pragma unroll
    for (int fi = 0; fi < 4; fi++) {
      #pragma unroll
      for (int r = 0; r < 4; r++) {
        #pragma unroll
        for (int fj = 0; fj < 4; fj++) {
          float sc = fmaf(-2.0f, acc[fi][fj][r], e2c[fj]);
          unsigned e = ((pk32(sc) >> 13) << 10) | (colbase + (unsigned)(fj * 16));
          mrg3(top3[fi][r][0], top3[fi][r][1], top3[fi][r][2], e);
        }
        #pragma unroll
        for (int fj = 0; fj < 4; fj++) acc[fi][fj][r] = 0.0f;
      }
    }
  }

  // ---- cross-lane merge; merge buffers alias Bb (loop done) ----
  __syncthreads();
  unsigned* mb = (unsigned*)Bb;            // sbuf=mb[0..1023], ssec=+1024, sthr=+2048
  #pragma unroll
  for (int fi = 0; fi < 4; fi++) {
    #pragma unroll
    for (int r = 0; r < 4; r++) {
      unsigned b = top3[fi][r][0], s2 = top3[fi][r][1], t3 = top3[fi][r][2];
      #pragma unroll
      for (int off = 1; off < 4; off <<= 1) {
        unsigned ob = __shfl_xor(b, off, 64);
        unsigned os = __shfl_xor(s2, off, 64);
        unsigned ot = __shfl_xor(t3, off, 64);
        mrg3(b, s2, t3, ob); mrg3(b, s2, t3, os); mrg3(b, s2, t3, ot);
      }
      if ((la & 3) == 0) {
        int tl = wm * 64 + fi * 16 + (lq << 2) + r;
        int slot = wn * 4 + (la >> 2);
        mb[tl * 8 + slot] = b;
        mb[1024 + tl * 8 + slot] = s2;
        mb[2048 + tl * 8 + slot] = t3;
      }
    }
  }
  __syncthreads();
  if (tid < 128) {
    unsigned B = 0xFFFFFFFFu, S = 0xFFFFFFFFu, T = 0xFFFFFFFFu;
    #pragma unroll
    for (int p = 0; p < 8; p++) {
      mrg3(B, S, T, mb[tid * 8 + p]);
      mrg3(B, S, T, mb[1024 + tid * 8 + p]);
      mrg3(B, S, T, mb[2048 + tid * 8 + p]);
    }
    const size_t o = (size_t)g * NTOK + t0 + tid;
    q0[o] = B; q1[o] = S; q2[o] = T;       // single writer: plain stores
  }
}

// ---------------- K3a: derive global top-2 from group top-3; build masks -----
// Global best = min over q0[g]; global second = min(2nd-smallest q0, q1 of the
// best group).  Ambiguous tokens emit {token, mask}: bits 0..7 = q0 in band,
// 8..15 = q1 in band, 16..23 = q2 in band (-> exact-scan that 1024-code group,
// since rank>=4 codes of that group could also be in band).
__global__ __launch_bounds__(256) void vq_reduce(const unsigned* __restrict__ q0,
                                                 const unsigned* __restrict__ q1,
                                                 const unsigned* __restrict__ q2,
                                                 unsigned* __restrict__ winners,
                                                 unsigned* __restrict__ work,
                                                 unsigned* __restrict__ cmask) {
  int t = blockIdx.x * 256 + threadIdx.x;
  unsigned v0[NGRP];
  unsigned b = 0xFFFFFFFFu, s = 0xFFFFFFFFu;
  int bg = 0;
  #pragma unroll
  for (int g = 0; g < NGRP; g++) {
    v0[g] = q0[(size_t)g * NTOK + t];
    if (v0[g] < b) { s = b; b = v0[g]; bg = g; }
    else if (v0[g] < s) { s = v0[g]; }
  }
  unsigned q1b = q1[(size_t)bg * NTOK + t];
  s = q1b < s ? q1b : s;
  float fb = upk32((b >> 10) << 13);
  float fs = upk32((s >> 10) << 13);
  if (fs > fb + DSELQ) { winners[t] = (unsigned)(bg * 1024) + (b & 1023u); return; }

  unsigned bk = pk32(fb + EPSF) >> 13;
  unsigned m = 0;
  #pragma unroll
  for (int g = 0; g < NGRP; g++) {
    if ((v0[g] >> 10) <= bk)                          m |= 1u << g;
    if ((q1[(size_t)g * NTOK + t] >> 10) <= bk)       m |= 1u << (8 + g);
    if ((q2[(size_t)g * NTOK + t] >> 10) <= bk)       m |= 1u << (16 + g);
  }
  unsigned w = atomicAdd(&work[0], 1u);
  work[1 + w] = (unsigned)t;
  cmask[w] = m;
}

// ---------------- K3b: exact fp32 resolution for ambiguous tokens ------------
// One wave per token.  Lanes 0-7/8-15/16-23 exdot the q0/q1/q2 entries of
// groups whose respective level is in band (skipped if the group is scanned).
// Groups whose q2 is in band are exact-scanned (1024 codes, 16 rounds) --
// covers any hidden rank>=4 candidate.  Completeness: a hidden code's key >=
// its group's q2 key, so "q2 key > bandkey" proves no hidden in-band code.
__global__ __launch_bounds__(64) void vq_chain(const float* __restrict__ z,
                                               const float* __restrict__ emb,
                                               const float* __restrict__ z2,
                                               const float* __restrict__ e2,
                                               const unsigned* __restrict__ q0,
                                               const unsigned* __restrict__ q1,
                                               const unsigned* __restrict__ q2,
                                               const unsigned* __restrict__ work,
                                               const unsigned* __restrict__ cmask,
                                               unsigned* __restrict__ winners) {
  __shared__ float zr[256];
  const int lane = threadIdx.x;
  const int nw = (int)work[0];

  for (int i = blockIdx.x; i < nw; i += gridDim.x) {
    int t = (int)work[1 + i];
    float4 zv = reinterpret_cast<const float4*>(z + (size_t)t * DIM)[lane];
    *reinterpret_cast<float4*>(&zr[lane * 4]) = zv;
    __syncthreads();
    const float z2t = z2[t];
    const unsigned m = cmask[i];
    const unsigned scanm = (m >> 16) & 0xFFu;

    unsigned long long best = ~0ull;
    if (lane < 24) {
      int lvl = lane >> 3;
      int g = lane & 7;
      bool on = (m >> (lvl * 8 + g)) & 1u;
      if (on && !((scanm >> g) & 1u)) {
        const unsigned* Q = (lvl == 0) ? q0 : ((lvl == 1) ? q1 : q2);
        unsigned e = Q[(size_t)g * NTOK + t];
        int cidx = g * 1024 + (int)(e & 1023u);
        best = exdot(emb, zr, z2t, e2, cidx);
      }
    }
    unsigned sc = scanm;
    while (sc) {
      int g = __ffs(sc) - 1;
      sc &= sc - 1;
      for (int r = 0; r < 16; r++) {
        int cidx = g * 1024 + r * 64 + lane;
        unsigned long long kk = exdot(emb, zr, z2t, e2, cidx);
        best = kk < best ? kk : best;
      }
    }
    #pragma unroll
    for (int off = 32; off > 0; off >>= 1) {
      unsigned long long o = __shfl_xor(best, off, 64);
      best = o < best ? o : best;
    }
    if (lane == 0) winners[t] = (unsigned)(best & 0xffffffffu);
    __syncthreads();
  }
}

// ---------------- K4: gather zq = emb[winner], idx, loss ---------------------
__global__ __launch_bounds__(256) void vq_emit(const float* __restrict__ z,
                                               const float* __restrict__ emb,
                                               const unsigned* __restrict__ winners,
                                               float* __restrict__ out_zq,
                                               float* __restrict__ out_loss,
                                               float* __restrict__ out_idx) {
  __shared__ float lsum[4];
  const int wid = threadIdx.x >> 6;
  const int lane = threadIdx.x & 63;
  const int tbase = blockIdx.x * 16 + wid * 4;
  float s_acc = 0.0f;
  #pragma unroll
  for (int it = 0; it < 4; it++) {
    int t = tbase + it;
    unsigned idx = winners[t];
    float4 e = reinterpret_cast<const float4*>(emb + (size_t)idx * DIM)[lane];
    float4 zz = reinterpret_cast<const float4*>(z + (size_t)t * DIM)[lane];
    reinterpret_cast<float4*>(out_zq + (size_t)t * DIM)[lane] = e;
    float dx = e.x - zz.x, dy = e.y - zz.y, dz = e.z - zz.z, dw = e.w - zz.w;
    s_acc += dx * dx + dy * dy + dz * dz + dw * dw;
    if (lane == 0) out_idx[t] = (float)idx;
  }
  #pragma unroll
  for (int off = 32; off > 0; off >>= 1) s_acc += __shfl_down(s_acc, off, 64);
  if (lane == 0) lsum[wid] = s_acc;
  __syncthreads();
  if (threadIdx.x == 0) {
    float tot = (lsum[0] + lsum[1] + lsum[2] + lsum[3]) * (1.25f / 8388608.0f);
    atomicAdd(out_loss, tot);
  }
}

// ====================== round-3 verified fallback path =======================
#define BT 128
#define BE 128
#define BK 32
#define LDW 132

__global__ __launch_bounds__(256) void fb_init(const float* __restrict__ z,
                                               const float* __restrict__ emb,
                                               float* __restrict__ e2,
                                               float* __restrict__ z2,
                                               unsigned long long* __restrict__ k1,
                                               float* __restrict__ loss_slot) {
  int gid = blockIdx.x * 256 + threadIdx.x;
  if (gid < NTOK) k1[gid] = ~0ull;
  if (gid == 0) loss_slot[0] = 0.0f;
  int wave = gid >> 6;
  int lane = threadIdx.x & 63;
  int row = wave * 16 + (lane >> 2);
  int sub = lane & 3;
  int q = sub & 1, h = sub >> 1;
  const float* src = (row < NTOK) ? (z + (size_t)row * DIM)
                                  : (emb + (size_t)(row - NTOK) * DIM);
  const float4* p = reinterpret_cast<const float4*>(src + h * 128 + q * 4);
  float r0, r1, r2, r3, s;
  {
    #pragma clang fp contract(off)
    r0 = 0.0f; r1 = 0.0f; r2 = 0.0f; r3 = 0.0f;
    #pragma unroll
    for (int t = 0; t < 16; t++) {
      float4 v = p[2 * t];
      float q0 = v.x * v.x, q1 = v.y * v.y, q2 = v.z * v.z, q3 = v.w * v.w;
      r0 = r0 + q0; r1 = r1 + q1; r2 = r2 + q2; r3 = r3 + q3;
    }
    s = (r0 + r1) + (r2 + r3);
    s = s + __shfl_xor(s, 1, 64);
    s = s + __shfl_xor(s, 2, 64);
  }
  if (sub == 0) {
    if (row < NTOK) z2[row] = s;
    else            e2[row - NTOK] = s;
  }
}

__global__ __launch_bounds__(256, 4) void fb_score(const float* __restrict__ z,
                                                   const float* __restrict__ emb,
                                                   const float* __restrict__ e2,
                                                   const float* __restrict__ z2,
                                                   unsigned long long* __restrict__ k1) {
  __shared__ float As[BK][LDW];
  __shared__ float Bs[BK][LDW];
  __shared__ unsigned long long mkey[BT];
  const int tid = threadIdx.x;
  const int t0 = blockIdx.x * BT;
  const int e0 = blockIdx.y * BE;
  const int tx = tid & 15;
  const int ty = tid >> 4;
  if (tid < BT) mkey[tid] = ~0ull;
  float acc[8][8];
  #pragma unroll
  for (int i = 0; i < 8; i++)
    #pragma unroll
    for (int j = 0; j < 8; j++) acc[i][j] = 0.0f;
  const float* __restrict__ zt = z + (size_t)t0 * DIM;
  const float* __restrict__ et = emb + (size_t)e0 * DIM;
  for (int kc = 0; kc < DIM; kc += BK) {
    __syncthreads();
    #pragma unroll
    for (int i = 0; i < 4; i++) {
      int f = tid + i * 256;
      int row = f >> 3;
      int kq = f & 7;
      const float4 va = *reinterpret_cast<const float4*>(zt + row * DIM + kc + kq * 4);
      const float4 vb = *reinterpret_cast<const float4*>(et + row * DIM + kc + kq * 4);
      int k = kq * 4;
      As[k + 0][row] = va.x * 2.0f; As[k + 1][row] = va.y * 2.0f;
      As[k + 2][row] = va.z * 2.0f; As[k + 3][row] = va.w * 2.0f;
      Bs[k + 0][row] = vb.x; Bs[k + 1][row] = vb.y;
      Bs[k + 2][row] = vb.z; Bs[k + 3][row] = vb.w;
    }
    __syncthreads();
    #pragma unroll 4
    for (int k = 0; k < BK; k++) {
      float a[8], b[8];
      *(float4*)&a[0] = *(const float4*)&As[k][ty * 8];
      *(float4*)&a[4] = *(const float4*)&As[k][ty * 8 + 4];
      *(float4*)&b[0] = *(const float4*)&Bs[k][tx * 8];
      *(float4*)&b[4] = *(const float4*)&Bs[k][tx * 8 + 4];
      #pragma unroll
      for (int i = 0; i < 8; i++)
        #pragma unroll
        for (int j = 0; j < 8; j++)
          acc[i][j] = fmaf(a[i], b[j], acc[i][j]);
    }
  }
  float e2c[8], z2t[8];
  *(float4*)&e2c[0] = *(const float4*)(e2 + e0 + tx * 8);
  *(float4*)&e2c[4] = *(const float4*)(e2 + e0 + tx * 8 + 4);
  *(float4*)&z2t[0] = *(const float4*)(z2 + t0 + ty * 8);
  *(float4*)&z2t[4] = *(const float4*)(z2 + t0 + ty * 8 + 4);
  {
    #pragma clang fp contract(off)
    #pragma unroll
    for (int i = 0; i < 8; i++) {
      int trow = ty * 8 + i;
      unsigned long long best = ~0ull;
      #pragma unroll
      for (int j = 0; j < 8; j++) {
        float t1 = z2t[i] - acc[i][j];
        float s = t1 + e2c[j];
        unsigned long long kk = pk64(s, e0 + tx * 8 + j);
        best = kk < best ? kk : best;
      }
      atomicMin(&mkey[trow], best);
    }
  }
  __syncthreads();
  if (tid < BT) atomicMin(&k1[t0 + tid], mkey[tid]);
}

__global__ __launch_bounds__(256) void fb_out(const float* __restrict__ z,
                                              const float* __restrict__ emb,
                                              const unsigned long long* __restrict__ k1,
                                              float* __restrict__ out_zq,
                                              float* __restrict__ out_loss,
                                              float* __restrict__ out_idx) {
  __shared__ float lsum[4];
  const int wid = threadIdx.x >> 6;
  const int lane = threadIdx.x & 63;
  const int tbase = blockIdx.x * 16 + wid * 4;
  float s_acc = 0.0f;
  #pragma unroll
  for (int it = 0; it < 4; it++) {
    int t = tbase + it;
    unsigned idx = (unsigned)(k1[t] & 0xffffffffu);
    float4 e = reinterpret_cast<const float4*>(emb + (size_t)idx * DIM)[lane];
    float4 zz = reinterpret_cast<const float4*>(z + (size_t)t * DIM)[lane];
    reinterpret_cast<float4*>(out_zq + (size_t)t * DIM)[lane] = e;
    float dx = e.x - zz.x, dy = e.y - zz.y, dz = e.z - zz.z, dw = e.w - zz.w;
    s_acc += dx * dx + dy * dy + dz * dz + dw * dw;
    if (lane == 0) out_idx[t] = (float)idx;
  }
  #pragma unroll
  for (int off = 32; off > 0; off >>= 1) s_acc += __shfl_down(s_acc, off, 64);
  if (lane == 0) lsum[wid] = s_acc;
  __syncthreads();
  if (threadIdx.x == 0) {
    float tot = (lsum[0] + lsum[1] + lsum[2] + lsum[3]) * (1.25f / 8388608.0f);
    atomicAdd(out_loss, tot);
  }
}

// ============================== launcher =====================================
extern "C" void kernel_launch(void* const* d_in, const int* in_sizes, int n_in,
                              void* d_out, int out_size, void* d_ws, size_t ws_size,
                              hipStream_t stream) {
  const float* z = (const float*)d_in[0];
  const float* emb = (const float*)d_in[1];
  float* out = (float*)d_out;
  float* out_zq = out;
  float* out_loss = out + (size_t)NTOK * DIM;
  float* out_idx = out_loss + 1;

  // ws: e2 | z2 | q0[8][NTOK] | q1 | q2 | work | cmask | winners | zb | eb
  const size_t OFF_Z2   = 32768;
  const size_t OFF_Q0   = 163840;
  const size_t OFF_Q1   = OFF_Q0 + (size_t)NGRP * NTOK * 4;    // 1212416
  const size_t OFF_Q2   = OFF_Q1 + (size_t)NGRP * NTOK * 4;    // 2260992
  const size_t OFF_WORK = OFF_Q2 + (size_t)NGRP * NTOK * 4;    // 3309568
  const size_t OFF_CM   = (OFF_WORK + 4 + 4 * (size_t)NTOK + 15) & ~(size_t)15; // 3440656
  const size_t OFF_WIN  = OFF_CM + 4 * (size_t)NTOK;           // 3571728
  const size_t OFF_ZB   = OFF_WIN + 4 * (size_t)NTOK;          // 3702800
  const size_t OFF_EB   = OFF_ZB + (size_t)NTOK * DIM * 2;     // 20480016
  const size_t REQ      = OFF_EB + (size_t)NE * DIM * 2;       // 24674320

  if (ws_size >= REQ) {
    float* e2 = (float*)d_ws;
    float* z2 = (float*)((char*)d_ws + OFF_Z2);
    unsigned* q0 = (unsigned*)((char*)d_ws + OFF_Q0);
    unsigned* q1 = (unsigned*)((char*)d_ws + OFF_Q1);
    unsigned* q2 = (unsigned*)((char*)d_ws + OFF_Q2);
    unsigned* work = (unsigned*)((char*)d_ws + OFF_WORK);
    unsigned* cmask = (unsigned*)((char*)d_ws + OFF_CM);
    unsigned* winners = (unsigned*)((char*)d_ws + OFF_WIN);
    unsigned short* zb = (unsigned short*)((char*)d_ws + OFF_ZB);
    unsigned short* eb = (unsigned short*)((char*)d_ws + OFF_EB);

    hipLaunchKernelGGL(vq_prep, dim3(640), dim3(256), 0, stream,
                       z, emb, e2, z2, work, zb, eb, out_loss);
    hipLaunchKernelGGL(vq_score, dim3(NGRP, NTOK / 128), dim3(256), 0, stream,
                       zb, eb, q0, q1, q2, e2);
    hipLaunchKernelGGL(vq_reduce, dim3(NTOK / 256), dim3(256), 0, stream,
                       q0, q1, q2, winners, work, cmask);
    hipLaunchKernelGGL(vq_chain, dim3(4096), dim3(64), 0, stream,
                       z, emb, z2, e2, q0, q1, q2, work, cmask, winners);
    hipLaunchKernelGGL(vq_emit, dim3(NTOK / 16), dim3(256), 0, stream,
                       z, emb, winners, out_zq, out_loss, out_idx);
  } else {
    float* e2 = (float*)d_ws;
    float* z2 = (float*)((char*)d_ws + 32768);
    unsigned long long* k1 = (unsigned long long*)((char*)d_ws + 262144);
    hipLaunchKernelGGL(fb_init, dim3(640), dim3(256), 0, stream,
                       z, emb, e2, z2, k1, out_loss);
    hipLaunchKernelGGL(fb_score, dim3(NTOK / BT, NE / BE), dim3(256), 0, stream,
                       z, emb, e2, z2, k1);
    hipLaunchKernelGGL(fb_out, dim3(NTOK / 16), dim3(256), 0, stream,
                       z, emb, k1, out_zq, out_loss, out_idx);
  }
}